// Round 9
// baseline (234.638 us; speedup 1.0000x reference)
//
#include <hip/hip_runtime.h>
#include <math.h>

// Problem constants (B=2, L=2048, D=512)
#define BB 2
#define LL 2048
#define DD 512
#define DIN 1024          // D_INNER
#define DXZ 2048          // 2*D_INNER
#define DSTATE 16
#define DTRANK 32
#define NDBL 64           // DT_RANK + 2*D_STATE
#define ML (BB*LL)        // 4096 rows
#define LC2 64            // scan chunk length
#define NCH2 (LL/LC2)     // 32 chunks per sequence
#define CP 68             // padded LDS chunk stride (floats)

typedef __bf16 bf16_t;
typedef bf16_t bf16x8 __attribute__((ext_vector_type(8)));
typedef bf16_t bf16x4 __attribute__((ext_vector_type(4)));
typedef float f32x4 __attribute__((ext_vector_type(4)));

#define GBK 32            // MFMA K-step
#define GBKP 40           // padded LDS row stride (bf16)

__device__ __forceinline__ float fast_silu(float x) {
  return x * __builtin_amdgcn_rcpf(1.f + __builtin_amdgcn_exp2f(-1.44269504f * x));
}

// ---------------------------------------------------------------------------
// bf16 MFMA GEMM: C[M,N] = A[M,K](bf16) * Bt[N,K](bf16)^T
// 256 threads = 4 waves (2x2). CT=1: store transposed C[n*ldc+m].
// MODE 0: plain; MODE 2: + aux[m*ldc+n] residual (CT=0 only).
// OB=1: output bf16 (CT=1 path only), else fp32.
// ---------------------------------------------------------------------------
template <int TM, int TN, int MODE, int CT, int OB>
__launch_bounds__(256)
__global__ void gemm_mfma(const bf16_t* __restrict__ A,
                          const bf16_t* __restrict__ Bt,
                          void* __restrict__ Cv, int ldc,
                          int M, int N, int K,
                          const float* __restrict__ aux) {
  __shared__ __align__(16) bf16_t As[TM * GBKP];
  __shared__ __align__(16) bf16_t Bs[TN * GBKP];
  float* C = (float*)Cv;
  bf16_t* Cb = (bf16_t*)Cv;
  const int tid = threadIdx.x;
  const int wid = tid >> 6, lane = tid & 63;
  const int q = lane >> 4, ln = lane & 15;
  constexpr int WM = TM / 2, WN = TN / 2;
  constexpr int FM = WM / 16, FN = WN / 16;
  const int wm = (wid >> 1) * WM, wn = (wid & 1) * WN;
  const int mBase = blockIdx.y * TM, nBase = blockIdx.x * TN;

  f32x4 acc[FM][FN] = {};

  for (int k0 = 0; k0 < K; k0 += GBK) {
#pragma unroll
    for (int i = 0; i < TM * GBK / (256 * 8); i++) {
      const int slot = tid + i * 256;
      const int m = slot >> 2, k8 = (slot & 3) * 8;
      *(bf16x8*)&As[m * GBKP + k8] =
          *(const bf16x8*)&A[(size_t)(mBase + m) * K + k0 + k8];
    }
#pragma unroll
    for (int i = 0; i < TN * GBK / (256 * 8); i++) {
      const int slot = tid + i * 256;
      const int n = slot >> 2, k8 = (slot & 3) * 8;
      *(bf16x8*)&Bs[n * GBKP + k8] =
          *(const bf16x8*)&Bt[(size_t)(nBase + n) * K + k0 + k8];
    }
    __syncthreads();
    bf16x8 af[FM], bfr[FN];
#pragma unroll
    for (int i = 0; i < FM; i++)
      af[i] = *(const bf16x8*)&As[(wm + i * 16 + ln) * GBKP + q * 8];
#pragma unroll
    for (int j = 0; j < FN; j++)
      bfr[j] = *(const bf16x8*)&Bs[(wn + j * 16 + ln) * GBKP + q * 8];
#pragma unroll
    for (int i = 0; i < FM; i++)
#pragma unroll
      for (int j = 0; j < FN; j++)
        acc[i][j] = __builtin_amdgcn_mfma_f32_16x16x32_bf16(
            af[i], bfr[j], acc[i][j], 0, 0, 0);
    __syncthreads();
  }

#pragma unroll
  for (int i = 0; i < FM; i++) {
    const int m0 = mBase + wm + i * 16 + q * 4;
#pragma unroll
    for (int j = 0; j < FN; j++) {
      const int n = nBase + wn + j * 16 + ln;
      if (CT == 1) {
        if (OB == 1) {
          bf16x4 o = {(bf16_t)acc[i][j][0], (bf16_t)acc[i][j][1],
                      (bf16_t)acc[i][j][2], (bf16_t)acc[i][j][3]};
          *(bf16x4*)&Cb[(size_t)n * ldc + m0] = o;
        } else {
          *(f32x4*)&C[(size_t)n * ldc + m0] = acc[i][j];
        }
      } else {
#pragma unroll
        for (int r = 0; r < 4; r++) {
          float v = acc[i][j][r];
          if (MODE == 2) v += aux[(size_t)(m0 + r) * ldc + n];
          C[(size_t)(m0 + r) * ldc + n] = v;
        }
      }
    }
  }
}

// ---------------------------------------------------------------------------
// Elementwise fp32 -> bf16 cast.
// ---------------------------------------------------------------------------
__global__ void cast_bf16(const float* __restrict__ in, bf16_t* __restrict__ out,
                          int n4) {
  const int i = blockIdx.x * 256 + threadIdx.x;
  if (i >= n4) return;
  const float4 v = ((const float4*)in)[i];
  bf16x4 o = {(bf16_t)v.x, (bf16_t)v.y, (bf16_t)v.z, (bf16_t)v.w};
  ((bf16x4*)out)[i] = o;
}

// ---------------------------------------------------------------------------
// Tiled transpose + cast: in TIN [R][C] -> out bf16 [C][R]. 64x64 tiles.
// ---------------------------------------------------------------------------
template <typename TIN>
__launch_bounds__(256)
__global__ void transpose_cast(const TIN* __restrict__ in, bf16_t* __restrict__ out,
                               int R, int C) {
  __shared__ float T[64][65];
  const int t = threadIdx.x;
  const int rB = blockIdx.y * 64, cB = blockIdx.x * 64;
  {
    const int r = t >> 4, c4 = (t & 15) * 4;
#pragma unroll
    for (int i = 0; i < 4; i++) {
      const TIN* src = &in[(size_t)(rB + r + i * 16) * C + cB + c4];
      float v0, v1, v2, v3;
      if (sizeof(TIN) == 4) {
        const float4 v = *(const float4*)src;
        v0 = v.x; v1 = v.y; v2 = v.z; v3 = v.w;
      } else {
        const bf16x4 v = *(const bf16x4*)src;
        v0 = (float)v[0]; v1 = (float)v[1]; v2 = (float)v[2]; v3 = (float)v[3];
      }
      T[r + i * 16][c4] = v0;
      T[r + i * 16][c4 + 1] = v1;
      T[r + i * 16][c4 + 2] = v2;
      T[r + i * 16][c4 + 3] = v3;
    }
  }
  __syncthreads();
  {
    const int c = t >> 2;
#pragma unroll
    for (int i = 0; i < 4; i++) {
      const int r0 = (t & 3) * 16 + i * 4;
      bf16x4 o = {(bf16_t)T[r0][c], (bf16_t)T[r0 + 1][c],
                  (bf16_t)T[r0 + 2][c], (bf16_t)T[r0 + 3][c]};
      *(bf16x4*)&out[(size_t)(cB + c) * R + rB + r0] = o;
    }
  }
}

// ---------------------------------------------------------------------------
// fp32 tiled GEMM (GEMM4 only): 64x64 tile, BK=16.
// MODE 1: softplus(acc+bias[n]); CT=1: transposed store.
// ---------------------------------------------------------------------------
template <int MODE, int AT, int CT>
__launch_bounds__(256)
__global__ void gemm_tiled(const float* __restrict__ A, int lda,
                           const float* __restrict__ B, int ldb,
                           float* __restrict__ C, int ldc,
                           int M, int N, int K,
                           const float* __restrict__ aux) {
  __shared__ float As[16][68];
  __shared__ float Bs[16][68];

  const int tid = threadIdx.x;
  const int tx = tid & 15, ty = tid >> 4;
  const int mBase = blockIdx.y * 64;
  const int nBase = blockIdx.x * 64;

  float acc[4][4] = {};

  for (int k0 = 0; k0 < K; k0 += 16) {
#pragma unroll
    for (int i = 0; i < 4; i++) {
      int idx = tid + i * 256;
      if (AT == 0) {
        int m = idx >> 4, kk = idx & 15;
        As[kk][m] = A[(size_t)(mBase + m) * lda + k0 + kk];
      } else {
        int kk = idx >> 6, m = idx & 63;
        As[kk][m] = A[(size_t)(k0 + kk) * lda + mBase + m];
      }
    }
#pragma unroll
    for (int i = 0; i < 4; i++) {
      int idx = tid + i * 256;
      int kk = idx >> 6, n = idx & 63;
      Bs[kk][n] = B[(size_t)(k0 + kk) * ldb + nBase + n];
    }
    __syncthreads();
#pragma unroll
    for (int kk = 0; kk < 16; kk++) {
      const float4 a4 = *reinterpret_cast<const float4*>(&As[kk][ty * 4]);
      const float4 b4 = *reinterpret_cast<const float4*>(&Bs[kk][tx * 4]);
      const float a[4] = {a4.x, a4.y, a4.z, a4.w};
      const float b[4] = {b4.x, b4.y, b4.z, b4.w};
#pragma unroll
      for (int i = 0; i < 4; i++)
#pragma unroll
        for (int j = 0; j < 4; j++) acc[i][j] = fmaf(a[i], b[j], acc[i][j]);
    }
    __syncthreads();
  }

  if (CT == 0) {
#pragma unroll
    for (int i = 0; i < 4; i++) {
      const int m = mBase + ty * 4 + i;
      const int n0 = nBase + tx * 4;
      float v[4];
#pragma unroll
      for (int j = 0; j < 4; j++) {
        float x = acc[i][j];
        if (MODE == 1) {
          x += aux[n0 + j];
          x = (x > 20.f) ? x
              : 0.69314718f * __builtin_amdgcn_logf(
                    1.f + __builtin_amdgcn_exp2f(x * 1.44269504f));
        }
        v[j] = x;
      }
      *reinterpret_cast<float4*>(&C[(size_t)m * ldc + n0]) =
          make_float4(v[0], v[1], v[2], v[3]);
    }
  } else {
    const int m0 = mBase + ty * 4;
#pragma unroll
    for (int j = 0; j < 4; j++) {
      const int n = nBase + tx * 4 + j;
      float v[4];
#pragma unroll
      for (int i = 0; i < 4; i++) {
        float x = acc[i][j];
        if (MODE == 1) {
          x += aux[n];
          x = (x > 20.f) ? x
              : 0.69314718f * __builtin_amdgcn_logf(
                    1.f + __builtin_amdgcn_exp2f(x * 1.44269504f));
        }
        v[i] = x;
      }
      *reinterpret_cast<float4*>(&C[(size_t)n * ldc + m0]) =
          make_float4(v[0], v[1], v[2], v[3]);
    }
  }
}

// ---------------------------------------------------------------------------
// Depthwise causal conv (k=4) + bias + SiLU. bf16 input (xzT rows 0..1023),
// fp32 output uT.
// ---------------------------------------------------------------------------
__launch_bounds__(256)
__global__ void conv_silu_T(const bf16_t* __restrict__ xzTb,
                            const float* __restrict__ conv_w,
                            const float* __restrict__ conv_b,
                            float* __restrict__ uT) {
  const int idx = blockIdx.x * 256 + threadIdx.x;   // over DIN * ML/4
  const int d = idx >> 10;
  const int ml0 = (idx & 1023) * 4;
  const int l0 = ml0 & (LL - 1);
  const bf16_t* row = xzTb + (size_t)d * ML + ml0;
  const bf16x4 Bv4 = *(const bf16x4*)row;
  bf16x4 Av4 = {(bf16_t)0.f, (bf16_t)0.f, (bf16_t)0.f, (bf16_t)0.f};
  if (l0 != 0) Av4 = *(const bf16x4*)(row - 4);
  const float Ay = (float)Av4[1], Az = (float)Av4[2], Aw = (float)Av4[3];
  const float Bx = (float)Bv4[0], By = (float)Bv4[1], Bz = (float)Bv4[2],
              Bw = (float)Bv4[3];
  const float w0 = conv_w[d * 4 + 0], w1 = conv_w[d * 4 + 1];
  const float w2 = conv_w[d * 4 + 2], w3 = conv_w[d * 4 + 3];
  const float bias = conv_b[d];
  float o[4];
  o[0] = bias + w0 * Ay + w1 * Az + w2 * Aw + w3 * Bx;
  o[1] = bias + w0 * Az + w1 * Aw + w2 * Bx + w3 * By;
  o[2] = bias + w0 * Aw + w1 * Bx + w2 * By + w3 * Bz;
  o[3] = bias + w0 * Bx + w1 * By + w2 * Bz + w3 * Bw;
#pragma unroll
  for (int i = 0; i < 4; i++) o[i] = fast_silu(o[i]);
  *reinterpret_cast<float4*>(uT + (size_t)d * ML + ml0) =
      make_float4(o[0], o[1], o[2], o[3]);
}

// ---------------------------------------------------------------------------
// Fused chunked selective scan v4b: 256 threads = 2 channels/block.
// Per channel: 128 threads, 4 lanes/chunk, 4 states/lane, LC2=64, NCH2=32.
// Phase 1 (serial, the only serial pass): h_loc recurrence; writes
//   y_loc+u*Dp into u_s slot, chunk-local inclusive cumsum sdt into dt_s
//   slot, end-state Hc and decay product Pc.
// Phase 2: per-channel serial combine -> Hin (in place of Pc).
// Phase 3 (parallel over l): y(l) += sum_s C_s*Hin_s*exp2(Al2_s*sdt(l)).
// Epilogue: coalesced gated bf16 write to DEDICATED yTb (xzTb read-only).
// Prefetch is clamped: never reads outside x_dbl.
// ---------------------------------------------------------------------------
__launch_bounds__(256, 3)
__global__ void scan_fused4(const float* __restrict__ dtT,
                            const float* __restrict__ uT,
                            const bf16_t* __restrict__ xzTb,
                            bf16_t* __restrict__ yTb,
                            const float* __restrict__ xdbl,
                            const float* __restrict__ A_log,
                            const float* __restrict__ D_param) {
  __shared__ float dt_s[2][NCH2 * CP];   // dt, then inclusive cumsum sdt
  __shared__ float u_s[2][NCH2 * CP];    // u, then y' = y_loc + u*Dp (+corr)
  __shared__ float Pc[2][NCH2][DSTATE];  // decay products, then Hin in place
  __shared__ float Hc[2][NCH2][DSTATE];
  __shared__ float Al2s[2][DSTATE];

  const int tid = threadIdx.x;
  const int half = tid >> 7;             // waves 0-1: ch A, waves 2-3: ch B
  const int ht = tid & 127;
  const int c = blockIdx.x * 2 + half;
  const int b = c >> 10, d = c & (DIN - 1);
  const size_t rowoff = (size_t)d * ML + (size_t)b * LL;
  const float* dtrow = dtT + rowoff;
  const float* urow  = uT + rowoff;
  const bf16_t* zrow = xzTb + (size_t)(DIN + d) * ML + (size_t)b * LL;
  bf16_t* yrow = yTb + rowoff;

  float* dts = dt_s[half];
  float* us  = u_s[half];

  // Stage dt,u rows (2048 fp32 each), coalesced float4.
#pragma unroll
  for (int i = 0; i < 4; i++) {
    const int idx = (ht + i * 128) * 4;
    const int la = (idx >> 6) * CP + (idx & 63);
    *(float4*)&dts[la] = *(const float4*)&dtrow[idx];
    *(float4*)&us[la]  = *(const float4*)&urow[idx];
  }
  if (ht < DSTATE)
    Al2s[half][ht] = -expf(A_log[d * DSTATE + ht]) * 1.44269504f;

  const int ch = ht >> 2, q = ht & 3;
  const int s0 = q * 4;
  const float* BC = xdbl + ((size_t)b * LL + (size_t)ch * LC2) * NDBL + DTRANK + s0;
  const float Dp = D_param[d];
  __syncthreads();

  float Al2[4];
#pragma unroll
  for (int k = 0; k < 4; k++) Al2[k] = Al2s[half][s0 + k];

  // Phase 1: serial local scan. 4-deep group-double-buffered B/C prefetch.
  {
    float* dp = dts + ch * CP;          // mutable: cumsum written in place
    float* up = us + ch * CP;
    float h0 = 0.f, h1 = 0.f, h2 = 0.f, h3 = 0.f, sdt = 0.f;
    float4 Bcur[4], Ccur[4];
#pragma unroll
    for (int i = 0; i < 4; i++) {
      Bcur[i] = *(const float4*)(BC + (size_t)i * NDBL);
      Ccur[i] = *(const float4*)(BC + (size_t)i * NDBL + DSTATE);
    }
    for (int g = 0; g < 16; g++) {
      const int gn = (g < 15) ? g + 1 : 15;   // clamp: last group re-reads itself
      float4 Bn[4], Cn[4];
#pragma unroll
      for (int i = 0; i < 4; i++) {
        Bn[i] = *(const float4*)(BC + (size_t)(gn * 4 + i) * NDBL);
        Cn[i] = *(const float4*)(BC + (size_t)(gn * 4 + i) * NDBL + DSTATE);
      }
#pragma unroll
      for (int i = 0; i < 4; i++) {
        const int l = g * 4 + i;
        const float dtv = dp[l];
        const float uv = up[l];
        const float dtu = dtv * uv;
        sdt += dtv;
        const float e0 = __builtin_amdgcn_exp2f(dtv * Al2[0]);
        const float e1 = __builtin_amdgcn_exp2f(dtv * Al2[1]);
        const float e2 = __builtin_amdgcn_exp2f(dtv * Al2[2]);
        const float e3 = __builtin_amdgcn_exp2f(dtv * Al2[3]);
        h0 = fmaf(h0, e0, dtu * Bcur[i].x);
        h1 = fmaf(h1, e1, dtu * Bcur[i].y);
        h2 = fmaf(h2, e2, dtu * Bcur[i].z);
        h3 = fmaf(h3, e3, dtu * Bcur[i].w);
        float p = fmaf(h0, Ccur[i].x,
                  fmaf(h1, Ccur[i].y, fmaf(h2, Ccur[i].z, h3 * Ccur[i].w)));
        p += __int_as_float(__builtin_amdgcn_ds_swizzle(__float_as_int(p), 0x041F));
        p += __int_as_float(__builtin_amdgcn_ds_swizzle(__float_as_int(p), 0x081F));
        // reads of dp[l]/up[l] above precede these writes (data dependence)
        if (q == i) {
          up[l] = p + uv * Dp;     // y_loc + skip
          dp[l] = sdt;             // chunk-local inclusive cumsum for phase 3
        }
      }
#pragma unroll
      for (int i = 0; i < 4; i++) { Bcur[i] = Bn[i]; Ccur[i] = Cn[i]; }
    }
    *(float4*)&Pc[half][ch][s0] = make_float4(
        __builtin_amdgcn_exp2f(Al2[0] * sdt), __builtin_amdgcn_exp2f(Al2[1] * sdt),
        __builtin_amdgcn_exp2f(Al2[2] * sdt), __builtin_amdgcn_exp2f(Al2[3] * sdt));
    *(float4*)&Hc[half][ch][s0] = make_float4(h0, h1, h2, h3);
  }
  __syncthreads();

  // Phase 2: per-channel serial combine; Hin overwrites Pc in place.
  if (ht < DSTATE) {
    float h = 0.f;
#pragma unroll
    for (int k = 0; k < NCH2; k++) {
      const float Pv = Pc[half][k][ht], Hv = Hc[half][k][ht];
      Pc[half][k][ht] = h;               // Hin for chunk k
      h = fmaf(h, Pv, Hv);
    }
  }
  __syncthreads();

  // Phase 3: parallel cross-chunk correction (no serial chain, no B loads).
  {
    float A16[16];
#pragma unroll
    for (int s = 0; s < 16; s++) A16[s] = Al2s[half][s];
#pragma unroll 4
    for (int i = 0; i < 16; i++) {
      const int l = ht + i * 128;
      const int ck = l >> 6;
      const int la = ck * CP + (l & 63);
      const float sdt = dts[la];
      const float* Crow = xdbl + ((size_t)b * LL + l) * NDBL + DTRANK + DSTATE;
      const float4 C0 = *(const float4*)(Crow + 0);
      const float4 C1 = *(const float4*)(Crow + 4);
      const float4 C2 = *(const float4*)(Crow + 8);
      const float4 C3 = *(const float4*)(Crow + 12);
      const float4 g0 = *(const float4*)&Pc[half][ck][0];
      const float4 g1 = *(const float4*)&Pc[half][ck][4];
      const float4 g2 = *(const float4*)&Pc[half][ck][8];
      const float4 g3 = *(const float4*)&Pc[half][ck][12];
      float corr = 0.f;
      corr = fmaf(C0.x * g0.x, __builtin_amdgcn_exp2f(A16[0] * sdt), corr);
      corr = fmaf(C0.y * g0.y, __builtin_amdgcn_exp2f(A16[1] * sdt), corr);
      corr = fmaf(C0.z * g0.z, __builtin_amdgcn_exp2f(A16[2] * sdt), corr);
      corr = fmaf(C0.w * g0.w, __builtin_amdgcn_exp2f(A16[3] * sdt), corr);
      corr = fmaf(C1.x * g1.x, __builtin_amdgcn_exp2f(A16[4] * sdt), corr);
      corr = fmaf(C1.y * g1.y, __builtin_amdgcn_exp2f(A16[5] * sdt), corr);
      corr = fmaf(C1.z * g1.z, __builtin_amdgcn_exp2f(A16[6] * sdt), corr);
      corr = fmaf(C1.w * g1.w, __builtin_amdgcn_exp2f(A16[7] * sdt), corr);
      corr = fmaf(C2.x * g2.x, __builtin_amdgcn_exp2f(A16[8] * sdt), corr);
      corr = fmaf(C2.y * g2.y, __builtin_amdgcn_exp2f(A16[9] * sdt), corr);
      corr = fmaf(C2.z * g2.z, __builtin_amdgcn_exp2f(A16[10] * sdt), corr);
      corr = fmaf(C2.w * g2.w, __builtin_amdgcn_exp2f(A16[11] * sdt), corr);
      corr = fmaf(C3.x * g3.x, __builtin_amdgcn_exp2f(A16[12] * sdt), corr);
      corr = fmaf(C3.y * g3.y, __builtin_amdgcn_exp2f(A16[13] * sdt), corr);
      corr = fmaf(C3.z * g3.z, __builtin_amdgcn_exp2f(A16[14] * sdt), corr);
      corr = fmaf(C3.w * g3.w, __builtin_amdgcn_exp2f(A16[15] * sdt), corr);
      us[la] += corr;
    }
  }
  __syncthreads();

  // Epilogue: coalesced gated write  y = y' * silu(z)  (bf16 in/out).
#pragma unroll
  for (int i = 0; i < 4; i++) {
    const int idx = (ht + i * 128) * 4;
    const int la = (idx >> 6) * CP + (idx & 63);
    const float4 y4 = *(const float4*)&us[la];
    const bf16x4 z4 = *(const bf16x4*)&zrow[idx];
    bf16x4 o = {(bf16_t)(y4.x * fast_silu((float)z4[0])),
                (bf16_t)(y4.y * fast_silu((float)z4[1])),
                (bf16_t)(y4.z * fast_silu((float)z4[2])),
                (bf16_t)(y4.w * fast_silu((float)z4[3]))};
    *(bf16x4*)&yrow[idx] = o;
  }
}

// ---------------------------------------------------------------------------
// Workspace layout (all regions dedicated; one simple WAR overlay y_b->u_b):
//   0..16MB   xzTb   bf16 [2048][4096]  (written step1; read-only after)
//  16..32MB   uT     fp32 [1024][4096]
//  32..33MB   x_dbl  fp32 [4096][64]
//  33..49MB   dtT    fp32 [1024][4096]  (no overlays)
//  49..57MB   u_b    bf16 [4096][1024]  (y_b overlays after u_b is dead)
//  57..65MB   yTb    bf16 [1024][4096]  (scan output)
//  65..69MB   x_b    bf16 [4096][512]
//  69..71MB   W_inT_b  [2048][512]
//  71..72MB   W_outT_b [512][1024]
//  72..72.1MB W_xT_b   [64][1024]
// Total ~72.1MB (<= proven ws budget from R4-R6).
// ---------------------------------------------------------------------------
extern "C" void kernel_launch(void* const* d_in, const int* in_sizes, int n_in,
                              void* d_out, int out_size, void* d_ws, size_t ws_size,
                              hipStream_t stream) {
  const float* x      = (const float*)d_in[0];
  const float* W_in   = (const float*)d_in[1];
  const float* conv_w = (const float*)d_in[2];
  const float* conv_b = (const float*)d_in[3];
  const float* W_x    = (const float*)d_in[4];
  const float* W_dt   = (const float*)d_in[5];
  const float* b_dt   = (const float*)d_in[6];
  const float* A_log  = (const float*)d_in[7];
  const float* D_par  = (const float*)d_in[8];
  const float* W_out  = (const float*)d_in[9];
  float* out = (float*)d_out;

  const size_t MB = 1 << 20;
  char* ws = (char*)d_ws;
  bf16_t* xzTb = (bf16_t*)ws;                    // 0..16MB
  float* uT    = (float*)(ws + 16 * MB);         // 16..32MB
  float* x_dbl = (float*)(ws + 32 * MB);         // 32..33MB
  float* dtT   = (float*)(ws + 33 * MB);         // 33..49MB
  bf16_t* u_b  = (bf16_t*)(ws + 49 * MB);        // 49..57MB
  bf16_t* y_b  = (bf16_t*)(ws + 49 * MB);        // overlay: u_b dead after step 3
  bf16_t* yTb  = (bf16_t*)(ws + 57 * MB);        // 57..65MB
  bf16_t* x_b      = (bf16_t*)(ws + 65 * MB);    // 65..69MB
  bf16_t* W_inT_b  = (bf16_t*)(ws + 69 * MB);    // 69..71MB
  bf16_t* W_outT_b = (bf16_t*)(ws + 71 * MB);    // 71..72MB
  bf16_t* W_xT_b   = (bf16_t*)(ws + 72 * MB);    // 72..72.125MB

  // 0) casts / weight transposes
  cast_bf16<<<(ML * DD / 4) / 256, 256, 0, stream>>>(x, x_b, ML * DD / 4);
  transpose_cast<float><<<dim3(DXZ / 64, DD / 64), 256, 0, stream>>>(W_in, W_inT_b, DD, DXZ);
  transpose_cast<float><<<dim3(1, DIN / 64), 256, 0, stream>>>(W_x, W_xT_b, DIN, NDBL);
  transpose_cast<float><<<dim3(DD / 64, DIN / 64), 256, 0, stream>>>(W_out, W_outT_b, DIN, DD);

  // 1) xzT = (x @ W_in)^T  bf16 MFMA, transposed bf16 store
  gemm_mfma<128, 128, 0, 1, 1><<<dim3(DXZ / 128, ML / 128), 256, 0, stream>>>(
      x_b, W_inT_b, xzTb, ML, ML, DXZ, DD, nullptr);

  // 2) uT = silu(causal_conv4(xzTb rows 0..1023) + conv_b)   (fp32 out)
  conv_silu_T<<<(DIN * (ML / 4)) / 256, 256, 0, stream>>>(xzTb, conv_w, conv_b, uT);

  // 2b) u_b = transpose_cast(uT) -> bf16 [4096][1024]
  transpose_cast<float><<<dim3(ML / 64, DIN / 64), 256, 0, stream>>>(uT, u_b, DIN, ML);

  // 3) x_dbl = u @ W_x  bf16 MFMA  (4096x1024)@(1024x64)
  gemm_mfma<64, 64, 0, 0, 0><<<dim3(1, ML / 64), 256, 0, stream>>>(
      u_b, W_xT_b, x_dbl, NDBL, ML, NDBL, DIN, nullptr);

  // 4) dtT = softplus(x_dbl[:, :32] @ W_dt + b_dt)^T  (fp32, K=32)
  gemm_tiled<1, 0, 1><<<dim3(DIN / 64, ML / 64), 256, 0, stream>>>(
      x_dbl, NDBL, W_dt, DIN, dtT, ML, ML, DIN, DTRANK, b_dt);

  // 5) fused chunked scan + gated epilogue -> yTb (dedicated, bf16)
  scan_fused4<<<BB * DIN / 2, 256, 0, stream>>>(dtT, uT, xzTb, yTb, x_dbl, A_log, D_par);

  // 5b) y_b = transpose(yTb) -> bf16 [4096][1024]  (overlays dead u_b)
  transpose_cast<bf16_t><<<dim3(ML / 64, DIN / 64), 256, 0, stream>>>(yTb, y_b, DIN, ML);

  // 6) out = x + y @ W_out  bf16 MFMA, residual fused
  gemm_mfma<128, 64, 2, 0, 0><<<dim3(DD / 64, ML / 128), 256, 0, stream>>>(
      y_b, W_outT_b, out, DD, ML, DD, DIN, x);
}

// Round 10
// 229.109 us; speedup vs baseline: 1.0241x; 1.0241x over previous
//
#include <hip/hip_runtime.h>
#include <math.h>

// Problem constants (B=2, L=2048, D=512)
#define BB 2
#define LL 2048
#define DD 512
#define DIN 1024          // D_INNER
#define DXZ 2048          // 2*D_INNER
#define DSTATE 16
#define DTRANK 32
#define NDBL 64           // DT_RANK + 2*D_STATE
#define ML (BB*LL)        // 4096 rows
#define LC2 64            // scan chunk length
#define NCH2 (LL/LC2)     // 32 chunks per sequence
#define CPH 72            // padded LDS chunk stride (bf16 elements; 144B rows)

typedef __bf16 bf16_t;
typedef bf16_t bf16x8 __attribute__((ext_vector_type(8)));
typedef bf16_t bf16x4 __attribute__((ext_vector_type(4)));
typedef float f32x4 __attribute__((ext_vector_type(4)));

#define GBK 32            // MFMA K-step
#define GBKP 40           // padded LDS row stride (bf16)

__device__ __forceinline__ float fast_silu(float x) {
  return x * __builtin_amdgcn_rcpf(1.f + __builtin_amdgcn_exp2f(-1.44269504f * x));
}

// ---------------------------------------------------------------------------
// bf16 MFMA GEMM: C[M,N] = A[M,K](bf16) * Bt[N,K](bf16)^T
// 256 threads = 4 waves (2x2). CT=1: store transposed C[n*ldc+m].
// MODE 0: plain; MODE 2: + aux[m*ldc+n] residual (CT=0 only).
// OB=1: output bf16 (CT=1 path only), else fp32.
// ---------------------------------------------------------------------------
template <int TM, int TN, int MODE, int CT, int OB>
__launch_bounds__(256)
__global__ void gemm_mfma(const bf16_t* __restrict__ A,
                          const bf16_t* __restrict__ Bt,
                          void* __restrict__ Cv, int ldc,
                          int M, int N, int K,
                          const float* __restrict__ aux) {
  __shared__ __align__(16) bf16_t As[TM * GBKP];
  __shared__ __align__(16) bf16_t Bs[TN * GBKP];
  float* C = (float*)Cv;
  bf16_t* Cb = (bf16_t*)Cv;
  const int tid = threadIdx.x;
  const int wid = tid >> 6, lane = tid & 63;
  const int q = lane >> 4, ln = lane & 15;
  constexpr int WM = TM / 2, WN = TN / 2;
  constexpr int FM = WM / 16, FN = WN / 16;
  const int wm = (wid >> 1) * WM, wn = (wid & 1) * WN;
  const int mBase = blockIdx.y * TM, nBase = blockIdx.x * TN;

  f32x4 acc[FM][FN] = {};

  for (int k0 = 0; k0 < K; k0 += GBK) {
#pragma unroll
    for (int i = 0; i < TM * GBK / (256 * 8); i++) {
      const int slot = tid + i * 256;
      const int m = slot >> 2, k8 = (slot & 3) * 8;
      *(bf16x8*)&As[m * GBKP + k8] =
          *(const bf16x8*)&A[(size_t)(mBase + m) * K + k0 + k8];
    }
#pragma unroll
    for (int i = 0; i < TN * GBK / (256 * 8); i++) {
      const int slot = tid + i * 256;
      const int n = slot >> 2, k8 = (slot & 3) * 8;
      *(bf16x8*)&Bs[n * GBKP + k8] =
          *(const bf16x8*)&Bt[(size_t)(nBase + n) * K + k0 + k8];
    }
    __syncthreads();
    bf16x8 af[FM], bfr[FN];
#pragma unroll
    for (int i = 0; i < FM; i++)
      af[i] = *(const bf16x8*)&As[(wm + i * 16 + ln) * GBKP + q * 8];
#pragma unroll
    for (int j = 0; j < FN; j++)
      bfr[j] = *(const bf16x8*)&Bs[(wn + j * 16 + ln) * GBKP + q * 8];
#pragma unroll
    for (int i = 0; i < FM; i++)
#pragma unroll
      for (int j = 0; j < FN; j++)
        acc[i][j] = __builtin_amdgcn_mfma_f32_16x16x32_bf16(
            af[i], bfr[j], acc[i][j], 0, 0, 0);
    __syncthreads();
  }

#pragma unroll
  for (int i = 0; i < FM; i++) {
    const int m0 = mBase + wm + i * 16 + q * 4;
#pragma unroll
    for (int j = 0; j < FN; j++) {
      const int n = nBase + wn + j * 16 + ln;
      if (CT == 1) {
        if (OB == 1) {
          bf16x4 o = {(bf16_t)acc[i][j][0], (bf16_t)acc[i][j][1],
                      (bf16_t)acc[i][j][2], (bf16_t)acc[i][j][3]};
          *(bf16x4*)&Cb[(size_t)n * ldc + m0] = o;
        } else {
          *(f32x4*)&C[(size_t)n * ldc + m0] = acc[i][j];
        }
      } else {
#pragma unroll
        for (int r = 0; r < 4; r++) {
          float v = acc[i][j][r];
          if (MODE == 2) v += aux[(size_t)(m0 + r) * ldc + n];
          C[(size_t)(m0 + r) * ldc + n] = v;
        }
      }
    }
  }
}

// ---------------------------------------------------------------------------
// Elementwise fp32 -> bf16 cast.
// ---------------------------------------------------------------------------
__global__ void cast_bf16(const float* __restrict__ in, bf16_t* __restrict__ out,
                          int n4) {
  const int i = blockIdx.x * 256 + threadIdx.x;
  if (i >= n4) return;
  const float4 v = ((const float4*)in)[i];
  bf16x4 o = {(bf16_t)v.x, (bf16_t)v.y, (bf16_t)v.z, (bf16_t)v.w};
  ((bf16x4*)out)[i] = o;
}

// ---------------------------------------------------------------------------
// Tiled transpose + cast: in TIN [R][C] -> out bf16 [C][R]. 64x64 tiles.
// ---------------------------------------------------------------------------
template <typename TIN>
__launch_bounds__(256)
__global__ void transpose_cast(const TIN* __restrict__ in, bf16_t* __restrict__ out,
                               int R, int C) {
  __shared__ float T[64][65];
  const int t = threadIdx.x;
  const int rB = blockIdx.y * 64, cB = blockIdx.x * 64;
  {
    const int r = t >> 4, c4 = (t & 15) * 4;
#pragma unroll
    for (int i = 0; i < 4; i++) {
      const TIN* src = &in[(size_t)(rB + r + i * 16) * C + cB + c4];
      float v0, v1, v2, v3;
      if (sizeof(TIN) == 4) {
        const float4 v = *(const float4*)src;
        v0 = v.x; v1 = v.y; v2 = v.z; v3 = v.w;
      } else {
        const bf16x4 v = *(const bf16x4*)src;
        v0 = (float)v[0]; v1 = (float)v[1]; v2 = (float)v[2]; v3 = (float)v[3];
      }
      T[r + i * 16][c4] = v0;
      T[r + i * 16][c4 + 1] = v1;
      T[r + i * 16][c4 + 2] = v2;
      T[r + i * 16][c4 + 3] = v3;
    }
  }
  __syncthreads();
  {
    const int c = t >> 2;
#pragma unroll
    for (int i = 0; i < 4; i++) {
      const int r0 = (t & 3) * 16 + i * 4;
      bf16x4 o = {(bf16_t)T[r0][c], (bf16_t)T[r0 + 1][c],
                  (bf16_t)T[r0 + 2][c], (bf16_t)T[r0 + 3][c]};
      *(bf16x4*)&out[(size_t)(cB + c) * R + rB + r0] = o;
    }
  }
}

// ---------------------------------------------------------------------------
// fp32 tiled GEMM: 64x64 tile, BK=16. Supports split-K via gridDim.z.
// AT: A layout [m][k] (0) or [k][m] (1).
// MODE 1: softplus(acc+bias[n]); MODE 3: atomicAdd epilogue (split-K).
// CT=1: transposed store (OB=1 -> bf16).
// ---------------------------------------------------------------------------
template <int MODE, int AT, int CT, int OB>
__launch_bounds__(256)
__global__ void gemm_tiled(const float* __restrict__ A, int lda,
                           const float* __restrict__ B, int ldb,
                           void* __restrict__ Cv, int ldc,
                           int M, int N, int K,
                           const float* __restrict__ aux) {
  __shared__ float As[16][68];
  __shared__ float Bs[16][68];
  float* C = (float*)Cv;
  bf16_t* Cb = (bf16_t*)Cv;

  const int tid = threadIdx.x;
  const int tx = tid & 15, ty = tid >> 4;
  const int mBase = blockIdx.y * 64;
  const int nBase = blockIdx.x * 64;
  const int kPer = K / gridDim.z;
  const int kBeg = blockIdx.z * kPer;

  float acc[4][4] = {};

  for (int k0 = kBeg; k0 < kBeg + kPer; k0 += 16) {
#pragma unroll
    for (int i = 0; i < 4; i++) {
      int idx = tid + i * 256;
      if (AT == 0) {
        int m = idx >> 4, kk = idx & 15;
        As[kk][m] = A[(size_t)(mBase + m) * lda + k0 + kk];
      } else {
        int kk = idx >> 6, m = idx & 63;
        As[kk][m] = A[(size_t)(k0 + kk) * lda + mBase + m];
      }
    }
#pragma unroll
    for (int i = 0; i < 4; i++) {
      int idx = tid + i * 256;
      int kk = idx >> 6, n = idx & 63;
      Bs[kk][n] = B[(size_t)(k0 + kk) * ldb + nBase + n];
    }
    __syncthreads();
#pragma unroll
    for (int kk = 0; kk < 16; kk++) {
      const float4 a4 = *reinterpret_cast<const float4*>(&As[kk][ty * 4]);
      const float4 b4 = *reinterpret_cast<const float4*>(&Bs[kk][tx * 4]);
      const float a[4] = {a4.x, a4.y, a4.z, a4.w};
      const float b[4] = {b4.x, b4.y, b4.z, b4.w};
#pragma unroll
      for (int i = 0; i < 4; i++)
#pragma unroll
        for (int j = 0; j < 4; j++) acc[i][j] = fmaf(a[i], b[j], acc[i][j]);
    }
    __syncthreads();
  }

  if (CT == 0) {
#pragma unroll
    for (int i = 0; i < 4; i++) {
      const int m = mBase + ty * 4 + i;
      const int n0 = nBase + tx * 4;
      if (MODE == 3) {
#pragma unroll
        for (int j = 0; j < 4; j++)
          atomicAdd(&C[(size_t)m * ldc + n0 + j], acc[i][j]);
      } else {
        float v[4];
#pragma unroll
        for (int j = 0; j < 4; j++) {
          float x = acc[i][j];
          if (MODE == 1) {
            x += aux[n0 + j];
            x = (x > 20.f) ? x
                : 0.69314718f * __builtin_amdgcn_logf(
                      1.f + __builtin_amdgcn_exp2f(x * 1.44269504f));
          }
          v[j] = x;
        }
        *reinterpret_cast<float4*>(&C[(size_t)m * ldc + n0]) =
            make_float4(v[0], v[1], v[2], v[3]);
      }
    }
  } else {
    const int m0 = mBase + ty * 4;
#pragma unroll
    for (int j = 0; j < 4; j++) {
      const int n = nBase + tx * 4 + j;
      float v[4];
#pragma unroll
      for (int i = 0; i < 4; i++) {
        float x = acc[i][j];
        if (MODE == 1) {
          x += aux[n];
          x = (x > 20.f) ? x
              : 0.69314718f * __builtin_amdgcn_logf(
                    1.f + __builtin_amdgcn_exp2f(x * 1.44269504f));
        }
        v[i] = x;
      }
      if (OB == 1) {
        bf16x4 o = {(bf16_t)v[0], (bf16_t)v[1], (bf16_t)v[2], (bf16_t)v[3]};
        *(bf16x4*)&Cb[(size_t)n * ldc + m0] = o;
      } else {
        *reinterpret_cast<float4*>(&C[(size_t)n * ldc + m0]) =
            make_float4(v[0], v[1], v[2], v[3]);
      }
    }
  }
}

// ---------------------------------------------------------------------------
// Depthwise causal conv (k=4) + bias + SiLU. bf16 input, fp32 output uT.
// ---------------------------------------------------------------------------
__launch_bounds__(256)
__global__ void conv_silu_T(const bf16_t* __restrict__ xzTb,
                            const float* __restrict__ conv_w,
                            const float* __restrict__ conv_b,
                            float* __restrict__ uT) {
  const int idx = blockIdx.x * 256 + threadIdx.x;   // over DIN * ML/4
  const int d = idx >> 10;
  const int ml0 = (idx & 1023) * 4;
  const int l0 = ml0 & (LL - 1);
  const bf16_t* row = xzTb + (size_t)d * ML + ml0;
  const bf16x4 Bv4 = *(const bf16x4*)row;
  bf16x4 Av4 = {(bf16_t)0.f, (bf16_t)0.f, (bf16_t)0.f, (bf16_t)0.f};
  if (l0 != 0) Av4 = *(const bf16x4*)(row - 4);
  const float Ay = (float)Av4[1], Az = (float)Av4[2], Aw = (float)Av4[3];
  const float Bx = (float)Bv4[0], By = (float)Bv4[1], Bz = (float)Bv4[2],
              Bw = (float)Bv4[3];
  const float w0 = conv_w[d * 4 + 0], w1 = conv_w[d * 4 + 1];
  const float w2 = conv_w[d * 4 + 2], w3 = conv_w[d * 4 + 3];
  const float bias = conv_b[d];
  float o[4];
  o[0] = bias + w0 * Ay + w1 * Az + w2 * Aw + w3 * Bx;
  o[1] = bias + w0 * Az + w1 * Aw + w2 * Bx + w3 * By;
  o[2] = bias + w0 * Aw + w1 * Bx + w2 * By + w3 * Bz;
  o[3] = bias + w0 * Bx + w1 * By + w2 * Bz + w3 * Bw;
#pragma unroll
  for (int i = 0; i < 4; i++) o[i] = fast_silu(o[i]);
  *reinterpret_cast<float4*>(uT + (size_t)d * ML + ml0) =
      make_float4(o[0], o[1], o[2], o[3]);
}

// ---------------------------------------------------------------------------
// Fused chunked selective scan v5: one block = one (b,d) channel, 128 thr.
// 4 lanes/chunk, 4 states/lane, LC2=64, NCH2=32. v3 serial structure
// (measured-best) + bf16 LDS staging of dt/u (13.3 KB -> ~12 blocks/CU).
// Phase 1: serial local scan -> Hc, Pc.  Phase 2: chunk combine -> Hin.
// Phase 3: serial re-scan from Hin, y' = C.h + u*Dp overwrites u slot (bf16).
// Epilogue: coalesced gated bf16 write to dedicated yTb.
// ---------------------------------------------------------------------------
__launch_bounds__(128, 4)
__global__ void scan_fused5(const bf16_t* __restrict__ dtTb,
                            const float* __restrict__ uT,
                            const bf16_t* __restrict__ xzTb,
                            bf16_t* __restrict__ yTb,
                            const float* __restrict__ xdbl,
                            const float* __restrict__ A_log,
                            const float* __restrict__ D_param) {
  __shared__ bf16_t dt_s[NCH2 * CPH];
  __shared__ bf16_t u_s[NCH2 * CPH];   // u, then y' after phase 3
  __shared__ float Pc[NCH2][DSTATE];   // decay products, then Hin in place
  __shared__ float Hc[NCH2][DSTATE];

  const int tid = threadIdx.x;
  const int c = blockIdx.x;
  const int b = c >> 10, d = c & (DIN - 1);
  const size_t rowoff = (size_t)d * ML + (size_t)b * LL;
  const bf16_t* dtrow = dtTb + rowoff;
  const float* urow = uT + rowoff;
  const bf16_t* zrow = xzTb + (size_t)(DIN + d) * ML + (size_t)b * LL;
  bf16_t* yrow = yTb + rowoff;

  // Stage dt (bf16 direct, 16B) and u (fp32 -> bf16), chunk-padded.
#pragma unroll
  for (int i = 0; i < 2; i++) {
    const int e = (tid + i * 128) * 8;
    const int la = (e >> 6) * CPH + (e & 63);
    *(bf16x8*)&dt_s[la] = *(const bf16x8*)&dtrow[e];
  }
#pragma unroll
  for (int i = 0; i < 4; i++) {
    const int e = (tid + i * 128) * 4;
    const int la = (e >> 6) * CPH + (e & 63);
    const float4 v = *(const float4*)&urow[e];
    bf16x4 o = {(bf16_t)v.x, (bf16_t)v.y, (bf16_t)v.z, (bf16_t)v.w};
    *(bf16x4*)&u_s[la] = o;
  }

  const int ch = tid >> 2, q = tid & 3;
  const int s0 = q * 4;
  float Al2[4];
#pragma unroll
  for (int k = 0; k < 4; k++)
    Al2[k] = -expf(A_log[d * DSTATE + s0 + k]) * 1.44269504f;
  const bf16_t* dp = dt_s + ch * CPH;
  bf16_t* up = u_s + ch * CPH;
  const float* BC = xdbl + ((size_t)b * LL + (size_t)ch * LC2) * NDBL + DTRANK + s0;
  const float Dp = D_param[d];
  __syncthreads();

  // Phase 1: serial local scan (h0=0) -> Hc, Pc. Clamped 4-group prefetch.
  {
    float h0 = 0.f, h1 = 0.f, h2 = 0.f, h3 = 0.f, sdt = 0.f;
    float4 Bcur[4];
#pragma unroll
    for (int i = 0; i < 4; i++)
      Bcur[i] = *(const float4*)(BC + (size_t)i * NDBL);
    for (int g = 0; g < 16; g++) {
      const int gn = (g < 15) ? g + 1 : 15;
      float4 Bn[4];
#pragma unroll
      for (int i = 0; i < 4; i++)
        Bn[i] = *(const float4*)(BC + (size_t)(gn * 4 + i) * NDBL);
#pragma unroll
      for (int i = 0; i < 4; i++) {
        const int l = g * 4 + i;
        const float dtv = (float)dp[l];
        const float dtu = dtv * (float)up[l];
        sdt += dtv;
        const float e0 = __builtin_amdgcn_exp2f(dtv * Al2[0]);
        const float e1 = __builtin_amdgcn_exp2f(dtv * Al2[1]);
        const float e2 = __builtin_amdgcn_exp2f(dtv * Al2[2]);
        const float e3 = __builtin_amdgcn_exp2f(dtv * Al2[3]);
        h0 = fmaf(h0, e0, dtu * Bcur[i].x);
        h1 = fmaf(h1, e1, dtu * Bcur[i].y);
        h2 = fmaf(h2, e2, dtu * Bcur[i].z);
        h3 = fmaf(h3, e3, dtu * Bcur[i].w);
      }
#pragma unroll
      for (int i = 0; i < 4; i++) Bcur[i] = Bn[i];
    }
    *(float4*)&Pc[ch][s0] = make_float4(
        __builtin_amdgcn_exp2f(Al2[0] * sdt), __builtin_amdgcn_exp2f(Al2[1] * sdt),
        __builtin_amdgcn_exp2f(Al2[2] * sdt), __builtin_amdgcn_exp2f(Al2[3] * sdt));
    *(float4*)&Hc[ch][s0] = make_float4(h0, h1, h2, h3);
  }
  __syncthreads();

  // Phase 2: serial combine over 32 chunks; Hin overwrites Pc in place.
  if (tid < DSTATE) {
    float h = 0.f;
#pragma unroll
    for (int k = 0; k < NCH2; k++) {
      const float Pv = Pc[k][tid], Hv = Hc[k][tid];
      Pc[k][tid] = h;                  // Hin for chunk k
      h = fmaf(h, Pv, Hv);
    }
  }
  __syncthreads();

  // Phase 3: serial re-scan from Hin; y' overwrites u slot (bf16).
  {
    const float4 H4 = *(const float4*)&Pc[ch][s0];
    float h0 = H4.x, h1 = H4.y, h2 = H4.z, h3 = H4.w;
    float4 Bcur[4], Ccur[4];
#pragma unroll
    for (int i = 0; i < 4; i++) {
      Bcur[i] = *(const float4*)(BC + (size_t)i * NDBL);
      Ccur[i] = *(const float4*)(BC + (size_t)i * NDBL + DSTATE);
    }
    for (int g = 0; g < 16; g++) {
      const int gn = (g < 15) ? g + 1 : 15;
      float4 Bn[4], Cn[4];
#pragma unroll
      for (int i = 0; i < 4; i++) {
        Bn[i] = *(const float4*)(BC + (size_t)(gn * 4 + i) * NDBL);
        Cn[i] = *(const float4*)(BC + (size_t)(gn * 4 + i) * NDBL + DSTATE);
      }
#pragma unroll
      for (int i = 0; i < 4; i++) {
        const int l = g * 4 + i;
        const float dtv = (float)dp[l];
        const float uv = (float)up[l];
        const float dtu = dtv * uv;
        const float e0 = __builtin_amdgcn_exp2f(dtv * Al2[0]);
        const float e1 = __builtin_amdgcn_exp2f(dtv * Al2[1]);
        const float e2 = __builtin_amdgcn_exp2f(dtv * Al2[2]);
        const float e3 = __builtin_amdgcn_exp2f(dtv * Al2[3]);
        h0 = fmaf(h0, e0, dtu * Bcur[i].x);
        h1 = fmaf(h1, e1, dtu * Bcur[i].y);
        h2 = fmaf(h2, e2, dtu * Bcur[i].z);
        h3 = fmaf(h3, e3, dtu * Bcur[i].w);
        float p = fmaf(h0, Ccur[i].x,
                  fmaf(h1, Ccur[i].y, fmaf(h2, Ccur[i].z, h3 * Ccur[i].w)));
        p += __int_as_float(__builtin_amdgcn_ds_swizzle(__float_as_int(p), 0x041F));
        p += __int_as_float(__builtin_amdgcn_ds_swizzle(__float_as_int(p), 0x081F));
        // reads of dp[l]/up[l] above precede this write (wave lockstep)
        if (q == i) up[l] = (bf16_t)(p + uv * Dp);   // y' into dead u slot
      }
#pragma unroll
      for (int i = 0; i < 4; i++) { Bcur[i] = Bn[i]; Ccur[i] = Cn[i]; }
    }
  }
  __syncthreads();

  // Epilogue: coalesced gated write  y = y' * silu(z)  (bf16 in/out).
#pragma unroll
  for (int i = 0; i < 4; i++) {
    const int e = (tid + i * 128) * 4;
    const int la = (e >> 6) * CPH + (e & 63);
    const bf16x4 y4 = *(const bf16x4*)&u_s[la];
    const bf16x4 z4 = *(const bf16x4*)&zrow[e];
    bf16x4 o = {(bf16_t)((float)y4[0] * fast_silu((float)z4[0])),
                (bf16_t)((float)y4[1] * fast_silu((float)z4[1])),
                (bf16_t)((float)y4[2] * fast_silu((float)z4[2])),
                (bf16_t)((float)y4[3] * fast_silu((float)z4[3]))};
    *(bf16x4*)&yrow[e] = o;
  }
}

// ---------------------------------------------------------------------------
// Workspace layout (all dedicated, no overlays):
//   0..16MB  xzTb bf16 [2048][4096]   16..32MB uT fp32 [1024][4096]
//  32..33MB  x_dbl fp32 [4096][64]    33..41MB dtTb bf16 [1024][4096]
//  41..49MB  yTb bf16 [1024][4096]    49..57MB y_b bf16 [4096][1024]
//  57..61MB  x_b bf16 [4096][512]     61..63MB W_inT_b   63..64MB W_outT_b
// ---------------------------------------------------------------------------
extern "C" void kernel_launch(void* const* d_in, const int* in_sizes, int n_in,
                              void* d_out, int out_size, void* d_ws, size_t ws_size,
                              hipStream_t stream) {
  const float* x      = (const float*)d_in[0];
  const float* W_in   = (const float*)d_in[1];
  const float* conv_w = (const float*)d_in[2];
  const float* conv_b = (const float*)d_in[3];
  const float* W_x    = (const float*)d_in[4];
  const float* W_dt   = (const float*)d_in[5];
  const float* b_dt   = (const float*)d_in[6];
  const float* A_log  = (const float*)d_in[7];
  const float* D_par  = (const float*)d_in[8];
  const float* W_out  = (const float*)d_in[9];
  float* out = (float*)d_out;

  const size_t MB = 1 << 20;
  char* ws = (char*)d_ws;
  bf16_t* xzTb = (bf16_t*)ws;                    // 0..16MB
  float* uT    = (float*)(ws + 16 * MB);         // 16..32MB
  float* x_dbl = (float*)(ws + 32 * MB);         // 32..33MB
  bf16_t* dtTb = (bf16_t*)(ws + 33 * MB);        // 33..41MB
  bf16_t* yTb  = (bf16_t*)(ws + 41 * MB);        // 41..49MB
  bf16_t* y_b  = (bf16_t*)(ws + 49 * MB);        // 49..57MB
  bf16_t* x_b      = (bf16_t*)(ws + 57 * MB);    // 57..61MB
  bf16_t* W_inT_b  = (bf16_t*)(ws + 61 * MB);    // 61..63MB
  bf16_t* W_outT_b = (bf16_t*)(ws + 63 * MB);    // 63..64MB

  // 0) casts / weight transposes
  cast_bf16<<<(ML * DD / 4) / 256, 256, 0, stream>>>(x, x_b, ML * DD / 4);
  transpose_cast<float><<<dim3(DXZ / 64, DD / 64), 256, 0, stream>>>(W_in, W_inT_b, DD, DXZ);
  transpose_cast<float><<<dim3(DD / 64, DIN / 64), 256, 0, stream>>>(W_out, W_outT_b, DIN, DD);

  // 1) xzT = (x @ W_in)^T  bf16 MFMA, transposed bf16 store
  gemm_mfma<128, 128, 0, 1, 1><<<dim3(DXZ / 128, ML / 128), 256, 0, stream>>>(
      x_b, W_inT_b, xzTb, ML, ML, DXZ, DD, nullptr);

  // 2) uT = silu(causal_conv4(xzTb rows 0..1023) + conv_b)   (fp32 out)
  conv_silu_T<<<(DIN * (ML / 4)) / 256, 256, 0, stream>>>(xzTb, conv_w, conv_b, uT);

  // 3) x_dbl = u @ W_x  (fp32, split-K=8, atomic accumulate; reads uT directly)
  hipMemsetAsync(x_dbl, 0, (size_t)ML * NDBL * 4, stream);
  gemm_tiled<3, 1, 0, 0><<<dim3(1, ML / 64, 8), 256, 0, stream>>>(
      uT, ML, W_x, NDBL, x_dbl, NDBL, ML, NDBL, DIN, nullptr);

  // 4) dtTb = softplus(x_dbl[:, :32] @ W_dt + b_dt)^T  (bf16 transposed store)
  gemm_tiled<1, 0, 1, 1><<<dim3(DIN / 64, ML / 64, 1), 256, 0, stream>>>(
      x_dbl, NDBL, W_dt, DIN, dtTb, ML, ML, DIN, DTRANK, b_dt);

  // 5) fused chunked scan + gated epilogue -> yTb (dedicated, bf16)
  scan_fused5<<<BB * DIN, 128, 0, stream>>>(dtTb, uT, xzTb, yTb, x_dbl, A_log, D_par);

  // 5b) y_b = transpose(yTb) -> bf16 [4096][1024]
  transpose_cast<bf16_t><<<dim3(ML / 64, DIN / 64), 256, 0, stream>>>(yTb, y_b, DIN, ML);

  // 6) out = x + y @ W_out  bf16 MFMA, residual fused
  gemm_mfma<128, 64, 2, 0, 0><<<dim3(DD / 64, ML / 128), 256, 0, stream>>>(
      y_b, W_outT_b, out, DD, ML, DD, DIN, x);
}